// Round 8
// baseline (161.266 us; speedup 1.0000x reference)
//
#include <hip/hip_runtime.h>
#include <hip/hip_fp16.h>

// RoI Align, ALIGNED=False, SCALE=160.
// feat: (N=8, C=256, H=160, W=160) fp32
// rois: (K=1024, 5) fp32 [b, x1, y1, x2, y2]
// out:  (K, C, 14, 14) fp32
//
// Structure (R8): spatial HALF-plane blocks so 2-3 blocks fit per CU and
// staging of one block overlaps compute of another (per-wave vmcnt queues are
// independent — intra-wave prefetch was proven structurally impossible in
// R4-R7 because compute's own VMEM loads FIFO-serialize behind any prefetch).
//  1) memsetAsync: zero 16 per-(batch,half) counters.
//  2) pass1_count: per-sample half = (y0c>=80); hierarchical count (LDS hist
//     + 16 global atomics per block).
//  3) prefix16: exclusive prefix -> stream offsets; zero placement cursors.
//  4) pass2_place: full 16B descriptor {bx_local|dyr|wq13|vy0|vy1, ax(half2),
//     outidx, 0}; block-reserved placement (LDS rank + one global atomicAdd
//     per (b,h) per block). Stream order nondeterministic, output fully
//     deterministic (each descriptor carries its own unique outidx).
//  5) main: block=(pairgrp, b, half): stage 81 rows x 160 of channels c0,c1
//     interleaved as half2 (51.9 KB LDS -> 2-3 blocks/CU); stream descriptors,
//     ds_read2-pair gathers, 2 stores/sample.

#define FM_N 8
#define FM_C 256
#define FM_H 160
#define FM_W 160
#define PLANE (FM_H * FM_W)     // 25600
#define PLANE4 (PLANE / 4)      // 6400
#define OH 14
#define OW 14
#define OSP (OH * OW)           // 196
#define KTOT (1024 * OSP)       // 200704 max samples (K=1024)
#define SCALE_HW 160.0f
#define MAIN_BLK 512
#define NCP 2                   // channel-pairs per block phase count
#define ROWS 81                 // half-plane rows (1 overlap row)
#define PL_ENT (ROWS * FM_W)    // 12960
#define PL_F4 (PL_ENT / 4)      // 3240

typedef float f4 __attribute__((ext_vector_type(4)));

// ws layout (int32 units):
//   [0..16)   cnt16[b*2+h]   (zeroed by hipMemsetAsync)
//   [16..32)  soff16         (exclusive prefix, sample units)
//   [32..48)  pos16          (placement cursors, zeroed by prefix16)
//   byte 256: samples[K*196] as uint4
#define WS_SAMPLES_BYTE_OFF 256

__global__ __launch_bounds__(256) void pass1_count(
    const float* __restrict__ rois, int total, int* __restrict__ ws) {
  __shared__ int hist[16];
  const int t = threadIdx.x;
  if (t < 16) hist[t] = 0;
  __syncthreads();
  const int g = blockIdx.x * 256 + t;
  if (g < total) {
    const int k = g / OSP;
    const int s = g - k * OSP;
    const int oy = s / OW;
    const int b = (int)rois[k * 5];
    const float y1 = rois[k * 5 + 2] * SCALE_HW;
    const float y2 = rois[k * 5 + 4] * SCALE_HW;
    const float gy = (float)oy * (1.0f / (OH - 1));
    const float iy = y1 + gy * (y2 - y1) - 0.5f;      // must match pass2
    const int y0 = (int)floorf(iy);
    const int y0c = min(max(y0, 0), FM_H - 1);
    const int h = (y0c >= 80) ? 1 : 0;
    atomicAdd(&hist[b * 2 + h], 1);
  }
  __syncthreads();
  if (t < 16 && hist[t]) atomicAdd(&ws[t], hist[t]);
}

__global__ void prefix16(int* __restrict__ ws) {
  if (threadIdx.x == 0) {
    int acc = 0;
    for (int i = 0; i < 16; ++i) {
      ws[16 + i] = acc;
      acc += ws[i];
      ws[32 + i] = 0;
    }
  }
}

__global__ __launch_bounds__(256) void pass2_place(
    const float* __restrict__ rois, int total, int* __restrict__ ws,
    uint4* __restrict__ samples) {
  __shared__ int hist[16];
  __shared__ int basel[16];
  __shared__ int soffl[16];
  const int t = threadIdx.x;
  if (t < 16) hist[t] = 0;
  __syncthreads();

  const int g = blockIdx.x * 256 + t;
  const bool act = g < total;
  uint4 sd = {0, 0, 0, 0};
  int bh = 0;
  if (act) {
    const int k = g / OSP;
    const int s = g - k * OSP;
    const int b = (int)rois[k * 5];
    const float x1 = rois[k * 5 + 1] * SCALE_HW;
    const float y1 = rois[k * 5 + 2] * SCALE_HW;
    const float x2 = rois[k * 5 + 3] * SCALE_HW;
    const float y2 = rois[k * 5 + 4] * SCALE_HW;

    const int oy = s / OW;
    const int ox = s - oy * OW;
    const float gx = (float)ox * (1.0f / (OW - 1));
    const float gy = (float)oy * (1.0f / (OH - 1));

    // ALIGNED=False index math collapses to ix = fx - 0.5
    const float ix = x1 + gx * (x2 - x1) - 0.5f;
    const float iy = y1 + gy * (y2 - y1) - 0.5f;

    const float fx0 = floorf(ix);
    const float fy0 = floorf(iy);
    const int x0 = (int)fx0;
    const int y0 = (int)fy0;
    const float wx1 = ix - fx0;
    const float wy1 = iy - fy0;

    const bool vx0 = (x0 >= 0 && x0 < FM_W);
    const bool vx1 = (x0 + 1 >= 0 && x0 + 1 < FM_W);
    const unsigned vy0 = (y0 >= 0 && y0 < FM_H) ? 1u : 0u;
    const unsigned vy1 = (y0 + 1 >= 0 && y0 + 1 < FM_H) ? 1u : 0u;

    const int x0c = min(max(x0, 0), FM_W - 1);
    const int x1c = min(max(x0 + 1, 0), FM_W - 1);
    const int y0c = min(max(y0, 0), FM_H - 1);
    const int y1c = min(max(y0 + 1, 0), FM_H - 1);

    const int o00 = y0c * FM_W + x0c;
    const int o01 = y0c * FM_W + x1c;
    // Left-base: corners are always {plane[bx], plane[bx+1]} (border cases
    // carry zero ax weight on the garbage side).
    const int bx = vx1 ? (o01 - 1) : o00;        // global, in [-1, 25599]
    const int h = (y0c >= 80) ? 1 : 0;           // same test as pass1
    const int row0 = h ? 79 : 0;
    const unsigned bxs = (unsigned)(bx - row0 * FM_W + 4);  // local + pad
    const unsigned dyr = (unsigned)(y1c - y0c);  // 0/1
    unsigned wq = (unsigned)(wy1 * 8192.0f + 0.5f);
    wq = wq > 8191u ? 8191u : wq;

    const __half2 axh = __floats2half2_rn((1.0f - wx1) * (vx0 ? 1.0f : 0.0f),
                                          wx1 * (vx1 ? 1.0f : 0.0f));
    sd.x = bxs | (dyr << 15) | (wq << 16) | (vy0 << 29) | (vy1 << 30);
    sd.y = *(const unsigned*)&axh;
    sd.z = (unsigned)(k * (FM_C * OSP) + s);     // out index (+ c*OSP later)
    bh = b * 2 + h;
  }
  const int rank = act ? atomicAdd(&hist[bh], 1) : 0;
  __syncthreads();
  if (t < 16) {
    basel[t] = hist[t] ? atomicAdd(&ws[32 + t], hist[t]) : 0;
    soffl[t] = ws[16 + t];
  }
  __syncthreads();
  if (act) samples[(size_t)soffl[bh] + basel[bh] + rank] = sd;
}

__global__ __launch_bounds__(MAIN_BLK, 4) void roi_align_main_kernel(
    const float* __restrict__ feat, const int* __restrict__ ws,
    const uint4* __restrict__ samples, float* __restrict__ out) {
  // 4 front pad + 81x160 half-plane (half2: lo=c0, hi=c0+1) + 4 back pad.
  __shared__ __align__(16) __half2 planeBuf[PL_ENT + 8];

  const int pg = blockIdx.x;       // pair-group
  const int b = blockIdx.y;
  const int h = blockIdx.z;
  const int t = threadIdx.x;
  const int row0 = h ? 79 : 0;

  const int scount = ws[b * 2 + h];
  const int soff = ws[16 + b * 2 + h];
  const uint4* __restrict__ stream = samples + soff;

  if (t < 4) {
    planeBuf[t] = __floats2half2_rn(0.0f, 0.0f);
    planeBuf[4 + PL_ENT + t] = __floats2half2_rn(0.0f, 0.0f);
  }

  for (int cp = 0; cp < NCP; ++cp) {
    const int c0 = 2 * (pg * NCP + cp);
    if (cp) __syncthreads();  // previous phase's readers done

    // ---- stage rows [row0, row0+81) of planes c0, c0+1, half2-interleaved
    const f4* __restrict__ srcA =
        (const f4*)(feat + ((size_t)b * FM_C + c0) * PLANE) + row0 * (FM_W / 4);
    const f4* __restrict__ srcB = srcA + PLANE4;
    uint4* __restrict__ pl4 = (uint4*)(planeBuf + 4);
    for (int i = t; i < PL_F4; i += MAIN_BLK) {
      const f4 a = srcA[i];
      const f4 bb = srcB[i];
      const __half2 h0 = __floats2half2_rn(a.x, bb.x);
      const __half2 h1 = __floats2half2_rn(a.y, bb.y);
      const __half2 h2 = __floats2half2_rn(a.z, bb.z);
      const __half2 h3 = __floats2half2_rn(a.w, bb.w);
      uint4 u;
      u.x = *(const unsigned*)&h0;
      u.y = *(const unsigned*)&h1;
      u.z = *(const unsigned*)&h2;
      u.w = *(const unsigned*)&h3;
      pl4[i] = u;
    }
    __syncthreads();

    // ---- gather all samples of this (b,h) stream for channels c0, c0+1
    float* __restrict__ outc = out + (size_t)c0 * OSP;
#pragma unroll 2
    for (int w = t; w < scount; w += MAIN_BLK) {
      const uint4 sd = stream[w];
      const int bxs = (int)(sd.x & 0x7FFFu);
      const int o10 = bxs + (int)((sd.x >> 15) & 1u) * FM_W;

      // adjacent-pair reads -> ds_read2_b32; each half2 = both channels
      const __half2 pL0 = planeBuf[bxs];
      const __half2 pR0 = planeBuf[bxs + 1];
      const __half2 pL1 = planeBuf[o10];
      const __half2 pR1 = planeBuf[o10 + 1];

      const __half2 ax = *(const __half2*)&sd.y;
      const __half2 axl = __half2half2(__low2half(ax));
      const __half2 axr = __half2half2(__high2half(ax));
      const __half2 hx0 = __hfma2(pR0, axr, __hmul2(pL0, axl));
      const __half2 hx1 = __hfma2(pR1, axr, __hmul2(pL1, axl));

      const float wy1 = (float)((sd.x >> 16) & 0x1FFFu) * (1.0f / 8192.0f);
      const float ay0 = ((sd.x >> 29) & 1u) ? (1.0f - wy1) : 0.0f;
      const float ay1 = ((sd.x >> 30) & 1u) ? wy1 : 0.0f;

      const float vA = ay0 * __low2float(hx0) + ay1 * __low2float(hx1);
      const float vB = ay0 * __high2float(hx0) + ay1 * __high2float(hx1);

      float* __restrict__ dst = outc + sd.z;
      dst[0] = vA;
      dst[OSP] = vB;
    }
  }
}

extern "C" void kernel_launch(void* const* d_in, const int* in_sizes, int n_in,
                              void* d_out, int out_size, void* d_ws, size_t ws_size,
                              hipStream_t stream) {
  const float* feat = (const float*)d_in[0];
  const float* rois = (const float*)d_in[1];
  float* out = (float*)d_out;
  int* ws = (int*)d_ws;
  uint4* samples = (uint4*)((char*)d_ws + WS_SAMPLES_BYTE_OFF);

  const int K = in_sizes[1] / 5;  // 1024
  const int total = K * OSP;
  const int nblk = (total + 255) / 256;

  hipMemsetAsync(d_ws, 0, 64, stream);                       // cnt16 = 0
  pass1_count<<<nblk, 256, 0, stream>>>(rois, total, ws);
  prefix16<<<1, 64, 0, stream>>>(ws);
  pass2_place<<<nblk, 256, 0, stream>>>(rois, total, ws, samples);
  roi_align_main_kernel<<<dim3(FM_C / 2 / NCP, FM_N, 2), MAIN_BLK, 0, stream>>>(
      feat, ws, samples, out);
}

// Round 9
// 131.578 us; speedup vs baseline: 1.2256x; 1.2256x over previous
//
#include <hip/hip_runtime.h>
#include <hip/hip_fp16.h>

// RoI Align, ALIGNED=False, SCALE=160.
// feat: (N=8, C=256, H=160, W=160) fp32
// rois: (K=1024, 5) fp32 [b, x1, y1, x2, y2]
// out:  (K, C, 14, 14) fp32
//
// R9 structure: half-plane blocks (51.9 KB LDS -> 3 blocks/CU) so staging of
// one block overlaps compute of co-resident blocks (independent per-wave
// vmcnt queues; intra-wave prefetch proven impossible R4-R7). R8's regression
// was atomic-scrambled descriptor order -> scattered stores; fixed here via
// the monotonicity of iy in oy: each ROI's rows split [0,c0) -> half0,
// [c0,14) -> half1, so per-k chunks stay contiguous and in s-order.
//  1) setup_kernel (1 block): c0[k] per ROI, per-(b,h) stream sizes + per-k
//     chunk offsets (LDS atomics; chunk order nondeterministic, but each
//     descriptor carries its own outidx -> output deterministic).
//  2) precompute_kernel: 16B descriptor per (k,s) written at its chunk slot:
//     {bx_local|dyr|wq13|vy0|vy1, ax(half2), outidx, -}.
//  3) main kernel: block=(pair, b, half): stage 81 rows x 160 of channels
//     c0,c0+1 interleaved as half2; stream descriptors; ds_read2-pair
//     gathers; contiguous-run stores.

#define FM_N 8
#define FM_C 256
#define FM_H 160
#define FM_W 160
#define PLANE (FM_H * FM_W)     // 25600
#define PLANE4 (PLANE / 4)      // 6400
#define OH 14
#define OW 14
#define OSP (OH * OW)           // 196
#define KMAX 1024
#define SCALE_HW 160.0f
#define MAIN_BLK 512
#define ROWS 81                 // half-plane rows (1 overlap row)
#define PL_ENT (ROWS * FM_W)    // 12960
#define PL_F4 (PL_ENT / 4)      // 3240
#define TAILPAD 172             // boundary-mismatch insurance (zeroed)

typedef float f4 __attribute__((ext_vector_type(4)));

// ws layout (int32 units):
//   [0..16)   cnt16[b*2+h]  (stream sizes, samples)
//   [16..32)  soff16        (exclusive prefix, samples)
//   [32..32+3*KMAX) kinfo[k] = {chunk0_abs, chunk1_abs, c0}
//   byte 12544: samples[K*196] as uint4
#define WS_KINFO_OFF 32
#define WS_SAMPLES_BYTE_OFF 12544

// Shared between setup & precompute so the half-split test is bit-identical.
__device__ __forceinline__ float iy_of(float y1, float y2, int oy) {
  return fmaf((float)oy * (1.0f / (OH - 1)), y2 - y1, y1) - 0.5f;
}

__global__ __launch_bounds__(1024) void setup_kernel(
    const float* __restrict__ rois, int K, int* __restrict__ ws) {
  __shared__ int cnt[16];
  __shared__ int soff[16];
  const int t = threadIdx.x;
  if (t < 16) cnt[t] = 0;
  __syncthreads();
  int posA = 0, posB = 0, c0 = 0, b = 0;
  if (t < K) {
    b = (int)rois[t * 5];
    const float y1 = rois[t * 5 + 2] * SCALE_HW;
    const float y2 = rois[t * 5 + 4] * SCALE_HW;
#pragma unroll
    for (int oy = 0; oy < OH; ++oy)
      c0 += (iy_of(y1, y2, oy) < 80.0f) ? 1 : 0;   // monotonic in oy
    posA = atomicAdd(&cnt[b * 2 + 0], c0 * OW);
    posB = atomicAdd(&cnt[b * 2 + 1], (OH - c0) * OW);
  }
  __syncthreads();
  if (t == 0) {
    int acc = 0;
    for (int i = 0; i < 16; ++i) { soff[i] = acc; acc += cnt[i]; }
  }
  __syncthreads();
  if (t < 16) { ws[t] = cnt[t]; ws[16 + t] = soff[t]; }
  if (t < K) {
    ws[WS_KINFO_OFF + 3 * t + 0] = soff[b * 2 + 0] + posA;
    ws[WS_KINFO_OFF + 3 * t + 1] = soff[b * 2 + 1] + posB;
    ws[WS_KINFO_OFF + 3 * t + 2] = c0;
  }
}

__global__ __launch_bounds__(256) void precompute_kernel(
    const float* __restrict__ rois, const int* __restrict__ ws, int total,
    uint4* __restrict__ samples) {
  const int g = blockIdx.x * 256 + threadIdx.x;
  if (g >= total) return;
  const int k = g / OSP;
  const int s = g - k * OSP;
  const int oy = s / OW;
  const int ox = s - oy * OW;

  const float x1 = rois[k * 5 + 1] * SCALE_HW;
  const float y1 = rois[k * 5 + 2] * SCALE_HW;
  const float x2 = rois[k * 5 + 3] * SCALE_HW;
  const float y2 = rois[k * 5 + 4] * SCALE_HW;

  // ALIGNED=False index math collapses to ix = fx - 0.5
  const float ix = fmaf((float)ox * (1.0f / (OW - 1)), x2 - x1, x1) - 0.5f;
  const float iy = iy_of(y1, y2, oy);

  const float fx0 = floorf(ix);
  const float fy0 = floorf(iy);
  const int x0 = (int)fx0;
  const int y0 = (int)fy0;
  const float wx1 = ix - fx0;
  const float wy1 = iy - fy0;

  const bool vx0 = (x0 >= 0 && x0 < FM_W);
  const bool vx1 = (x0 + 1 >= 0 && x0 + 1 < FM_W);
  const unsigned vy0 = (y0 >= 0 && y0 < FM_H) ? 1u : 0u;
  const unsigned vy1 = (y0 + 1 >= 0 && y0 + 1 < FM_H) ? 1u : 0u;

  const int x0c = min(max(x0, 0), FM_W - 1);
  const int x1c = min(max(x0 + 1, 0), FM_W - 1);
  const int y0c = min(max(y0, 0), FM_H - 1);
  const int y1c = min(max(y0 + 1, 0), FM_H - 1);

  const int o00 = y0c * FM_W + x0c;
  const int o01 = y0c * FM_W + x1c;
  // Left-base: corners are always {plane[bx], plane[bx+1]} (border cases
  // carry zero ax weight on the garbage side).
  const int bx = vx1 ? (o01 - 1) : o00;

  const int ca = ws[WS_KINFO_OFF + 3 * k + 0];
  const int cb = ws[WS_KINFO_OFF + 3 * k + 1];
  const int c0 = ws[WS_KINFO_OFF + 3 * k + 2];
  const int h = (oy >= c0) ? 1 : 0;              // == (iy >= 80) by monotonicity
  const int row0 = h ? 79 : 0;
  const unsigned bxs = (unsigned)(bx - row0 * FM_W + 4);  // local + front pad
  const unsigned dyr = (unsigned)(y1c - y0c);    // 0/1
  unsigned wq = (unsigned)(wy1 * 8192.0f + 0.5f);
  wq = wq > 8191u ? 8191u : wq;

  const __half2 axh = __floats2half2_rn((1.0f - wx1) * (vx0 ? 1.0f : 0.0f),
                                        wx1 * (vx1 ? 1.0f : 0.0f));
  uint4 sd;
  sd.x = bxs | (dyr << 15) | (wq << 16) | (vy0 << 29) | (vy1 << 30);
  sd.y = *(const unsigned*)&axh;
  sd.z = (unsigned)(k * (FM_C * OSP) + s);       // out index (+ c*OSP later)
  sd.w = 0;

  const int pos = h ? (cb + (oy - c0) * OW + ox) : (ca + oy * OW + ox);
  samples[pos] = sd;
}

__global__ __launch_bounds__(MAIN_BLK) void roi_align_main_kernel(
    const float* __restrict__ feat, const int* __restrict__ ws,
    const uint4* __restrict__ samples, float* __restrict__ out) {
  // 4 front pad + 81x160 half-plane (half2: lo=c0, hi=c0+1) + zeroed tail pad
  // (tail absorbs the one-row overshoot if the fp half-split ever disagrees).
  __shared__ __align__(16) __half2 planeBuf[4 + PL_ENT + TAILPAD];

  const int pg = blockIdx.x;       // channel-pair index (0..127)
  const int b = blockIdx.y;
  const int h = blockIdx.z;
  const int t = threadIdx.x;
  const int row0 = h ? 79 : 0;
  const int c0ch = 2 * pg;

  const int scount = ws[b * 2 + h];
  const int soff = ws[16 + b * 2 + h];
  const uint4* __restrict__ stream = samples + soff;

  if (t < 4) planeBuf[t] = __floats2half2_rn(0.0f, 0.0f);
  if (t < TAILPAD) planeBuf[4 + PL_ENT + t] = __floats2half2_rn(0.0f, 0.0f);

  // ---- stage rows [row0, row0+81) of planes c0ch, c0ch+1, half2-interleaved
  const f4* __restrict__ srcA =
      (const f4*)(feat + ((size_t)b * FM_C + c0ch) * PLANE) + row0 * (FM_W / 4);
  const f4* __restrict__ srcB = srcA + PLANE4;
  uint4* __restrict__ pl4 = (uint4*)(planeBuf + 4);
  for (int i = t; i < PL_F4; i += MAIN_BLK) {
    const f4 a = srcA[i];
    const f4 bb = srcB[i];
    const __half2 h0 = __floats2half2_rn(a.x, bb.x);
    const __half2 h1 = __floats2half2_rn(a.y, bb.y);
    const __half2 h2 = __floats2half2_rn(a.z, bb.z);
    const __half2 h3 = __floats2half2_rn(a.w, bb.w);
    uint4 u;
    u.x = *(const unsigned*)&h0;
    u.y = *(const unsigned*)&h1;
    u.z = *(const unsigned*)&h2;
    u.w = *(const unsigned*)&h3;
    pl4[i] = u;
  }
  __syncthreads();

  // ---- gather all samples of this (b,h) stream for channels c0ch, c0ch+1
  float* __restrict__ outc = out + (size_t)c0ch * OSP;
#pragma unroll 4
  for (int w = t; w < scount; w += MAIN_BLK) {
    const uint4 sd = stream[w];
    const int bxs = (int)(sd.x & 0x7FFFu);
    const int o10 = bxs + (int)((sd.x >> 15) & 1u) * FM_W;

    // adjacent-pair reads -> ds_read2_b32; each half2 = both channels
    const __half2 pL0 = planeBuf[bxs];
    const __half2 pR0 = planeBuf[bxs + 1];
    const __half2 pL1 = planeBuf[o10];
    const __half2 pR1 = planeBuf[o10 + 1];

    const __half2 ax = *(const __half2*)&sd.y;
    const __half2 axl = __half2half2(__low2half(ax));
    const __half2 axr = __half2half2(__high2half(ax));
    const __half2 hx0 = __hfma2(pR0, axr, __hmul2(pL0, axl));
    const __half2 hx1 = __hfma2(pR1, axr, __hmul2(pL1, axl));

    const float wy1 = (float)((sd.x >> 16) & 0x1FFFu) * (1.0f / 8192.0f);
    const float ay0 = ((sd.x >> 29) & 1u) ? (1.0f - wy1) : 0.0f;
    const float ay1 = ((sd.x >> 30) & 1u) ? wy1 : 0.0f;

    const float vA = ay0 * __low2float(hx0) + ay1 * __low2float(hx1);
    const float vB = ay0 * __high2float(hx0) + ay1 * __high2float(hx1);

    float* __restrict__ dst = outc + sd.z;
    dst[0] = vA;
    dst[OSP] = vB;
  }
}

extern "C" void kernel_launch(void* const* d_in, const int* in_sizes, int n_in,
                              void* d_out, int out_size, void* d_ws, size_t ws_size,
                              hipStream_t stream) {
  const float* feat = (const float*)d_in[0];
  const float* rois = (const float*)d_in[1];
  float* out = (float*)d_out;
  int* ws = (int*)d_ws;
  uint4* samples = (uint4*)((char*)d_ws + WS_SAMPLES_BYTE_OFF);

  const int K = in_sizes[1] / 5;  // 1024
  const int total = K * OSP;

  setup_kernel<<<1, 1024, 0, stream>>>(rois, K, ws);
  precompute_kernel<<<(total + 255) / 256, 256, 0, stream>>>(rois, ws, total,
                                                             samples);
  roi_align_main_kernel<<<dim3(FM_C / 2, FM_N, 2), MAIN_BLK, 0, stream>>>(
      feat, ws, samples, out);
}

// Round 10
// 127.988 us; speedup vs baseline: 1.2600x; 1.0280x over previous
//
#include <hip/hip_runtime.h>
#include <hip/hip_fp16.h>

// RoI Align, ALIGNED=False, SCALE=160.
// feat: (N=8, C=256, H=160, W=160) fp32
// rois: (K=1024, 5) fp32 [b, x1, y1, x2, y2]
// out:  (K, C, 14, 14) fp32
//
// R10 structure: producer/consumer WAVE specialization with double-buffered
// HALF-plane LDS (2 x 51.9 KB fits 160 KB; full pair-planes would not).
// Waves 0-3 stage phase p+1 while waves 4-15 compute phase p — independent
// per-wave vmcnt queues give the stage/compute overlap that intra-wave
// prefetch (R4-R7) and block co-residency (R9 lockstep) could not.
//  1) setup_kernel (1 block): per-ROI half split c0[k] (iy monotonic in oy),
//     per-(b,h) stream sizes + per-k chunk offsets.
//  2) precompute_kernel: 16B descriptor per (k,s) at its in-order chunk slot:
//     {bx_local|dyr|wq13|vy0|vy1, ax(half2), outidx, -}. Deterministic output
//     (each descriptor carries its own unique outidx).
//  3) main kernel: block=(b, 4 channel-pairs) x 8 phases (pair, half).

#define FM_N 8
#define FM_C 256
#define FM_H 160
#define FM_W 160
#define PLANE (FM_H * FM_W)     // 25600
#define PLANE4 (PLANE / 4)      // 6400
#define OH 14
#define OW 14
#define OSP (OH * OW)           // 196
#define KMAX 1024
#define SCALE_HW 160.0f
#define MAIN_BLK 1024
#define NPROD 4                 // producer waves; 12 consumer waves
#define NCP 4                   // channel-pairs per block
#define NPHASE (2 * NCP)        // (pair, half) phases
#define ROWS 81                 // half-plane rows (1 overlap row)
#define PL_ENT (ROWS * FM_W)    // 12960
#define PL_F4 (PL_ENT / 4)      // 3240
#define TAILPAD 172             // boundary insurance (zeroed)

typedef float f4 __attribute__((ext_vector_type(4)));

// ws layout (int32 units):
//   [0..16)   cnt16[b*2+h]  (stream sizes, samples)
//   [16..32)  soff16        (exclusive prefix, samples)
//   [32..32+3*KMAX) kinfo[k] = {chunk0_abs, chunk1_abs, c0}
//   byte 12544: samples[K*196] as uint4
#define WS_KINFO_OFF 32
#define WS_SAMPLES_BYTE_OFF 12544

// Shared between setup & precompute so the half-split test is bit-identical.
__device__ __forceinline__ float iy_of(float y1, float y2, int oy) {
  return fmaf((float)oy * (1.0f / (OH - 1)), y2 - y1, y1) - 0.5f;
}

__global__ __launch_bounds__(1024) void setup_kernel(
    const float* __restrict__ rois, int K, int* __restrict__ ws) {
  __shared__ int cnt[16];
  __shared__ int soff[16];
  const int t = threadIdx.x;
  if (t < 16) cnt[t] = 0;
  __syncthreads();
  int posA = 0, posB = 0, c0 = 0, b = 0;
  if (t < K) {
    b = (int)rois[t * 5];
    const float y1 = rois[t * 5 + 2] * SCALE_HW;
    const float y2 = rois[t * 5 + 4] * SCALE_HW;
#pragma unroll
    for (int oy = 0; oy < OH; ++oy)
      c0 += (iy_of(y1, y2, oy) < 80.0f) ? 1 : 0;   // monotonic in oy
    posA = atomicAdd(&cnt[b * 2 + 0], c0 * OW);
    posB = atomicAdd(&cnt[b * 2 + 1], (OH - c0) * OW);
  }
  __syncthreads();
  if (t == 0) {
    int acc = 0;
    for (int i = 0; i < 16; ++i) { soff[i] = acc; acc += cnt[i]; }
  }
  __syncthreads();
  if (t < 16) { ws[t] = cnt[t]; ws[16 + t] = soff[t]; }
  if (t < K) {
    ws[WS_KINFO_OFF + 3 * t + 0] = soff[b * 2 + 0] + posA;
    ws[WS_KINFO_OFF + 3 * t + 1] = soff[b * 2 + 1] + posB;
    ws[WS_KINFO_OFF + 3 * t + 2] = c0;
  }
}

__global__ __launch_bounds__(256) void precompute_kernel(
    const float* __restrict__ rois, const int* __restrict__ ws, int total,
    uint4* __restrict__ samples) {
  const int g = blockIdx.x * 256 + threadIdx.x;
  if (g >= total) return;
  const int k = g / OSP;
  const int s = g - k * OSP;
  const int oy = s / OW;
  const int ox = s - oy * OW;

  const float x1 = rois[k * 5 + 1] * SCALE_HW;
  const float y1 = rois[k * 5 + 2] * SCALE_HW;
  const float x2 = rois[k * 5 + 3] * SCALE_HW;
  const float y2 = rois[k * 5 + 4] * SCALE_HW;

  // ALIGNED=False index math collapses to ix = fx - 0.5
  const float ix = fmaf((float)ox * (1.0f / (OW - 1)), x2 - x1, x1) - 0.5f;
  const float iy = iy_of(y1, y2, oy);

  const float fx0 = floorf(ix);
  const float fy0 = floorf(iy);
  const int x0 = (int)fx0;
  const int y0 = (int)fy0;
  const float wx1 = ix - fx0;
  const float wy1 = iy - fy0;

  const bool vx0 = (x0 >= 0 && x0 < FM_W);
  const bool vx1 = (x0 + 1 >= 0 && x0 + 1 < FM_W);
  const unsigned vy0 = (y0 >= 0 && y0 < FM_H) ? 1u : 0u;
  const unsigned vy1 = (y0 + 1 >= 0 && y0 + 1 < FM_H) ? 1u : 0u;

  const int x0c = min(max(x0, 0), FM_W - 1);
  const int x1c = min(max(x0 + 1, 0), FM_W - 1);
  const int y0c = min(max(y0, 0), FM_H - 1);
  const int y1c = min(max(y0 + 1, 0), FM_H - 1);

  const int o00 = y0c * FM_W + x0c;
  const int o01 = y0c * FM_W + x1c;
  // Left-base: corners are always {plane[bx], plane[bx+1]} (border cases
  // carry zero ax weight on the garbage side).
  const int bx = vx1 ? (o01 - 1) : o00;

  const int ca = ws[WS_KINFO_OFF + 3 * k + 0];
  const int cb = ws[WS_KINFO_OFF + 3 * k + 1];
  const int c0 = ws[WS_KINFO_OFF + 3 * k + 2];
  const int h = (oy >= c0) ? 1 : 0;              // == (iy >= 80) by monotonicity
  const int row0 = h ? 79 : 0;
  const unsigned bxs = (unsigned)(bx - row0 * FM_W + 4);  // local + front pad
  const unsigned dyr = (unsigned)(y1c - y0c);    // 0/1
  unsigned wq = (unsigned)(wy1 * 8192.0f + 0.5f);
  wq = wq > 8191u ? 8191u : wq;

  const __half2 axh = __floats2half2_rn((1.0f - wx1) * (vx0 ? 1.0f : 0.0f),
                                        wx1 * (vx1 ? 1.0f : 0.0f));
  uint4 sd;
  sd.x = bxs | (dyr << 15) | (wq << 16) | (vy0 << 29) | (vy1 << 30);
  sd.y = *(const unsigned*)&axh;
  sd.z = (unsigned)(k * (FM_C * OSP) + s);       // out index (+ c*OSP later)
  sd.w = 0;

  const int pos = h ? (cb + (oy - c0) * OW + ox) : (ca + oy * OW + ox);
  samples[pos] = sd;
}

__global__ __launch_bounds__(MAIN_BLK) void roi_align_main_kernel(
    const float* __restrict__ feat, const int* __restrict__ ws,
    const uint4* __restrict__ samples, float* __restrict__ out) {
  // Double-buffered half-plane: [4 front pad][81x160 half2][zero tail pad].
  __shared__ __align__(16) __half2 buf[2][4 + PL_ENT + TAILPAD];  // 105 KB

  const int b = blockIdx.y;
  const int pg0 = blockIdx.x * NCP;   // first channel-pair of this block
  const int t = threadIdx.x;
  const int wave = t >> 6;

  const int cntH0 = ws[b * 2 + 0], cntH1 = ws[b * 2 + 1];
  const int soffH0 = ws[16 + b * 2 + 0], soffH1 = ws[16 + b * 2 + 1];

  const __half2 hz = __floats2half2_rn(0.0f, 0.0f);
  if (t < 4) { buf[0][t] = hz; buf[1][t] = hz; }
  if (t < TAILPAD) {
    buf[0][4 + PL_ENT + t] = hz;
    buf[1][4 + PL_ENT + t] = hz;
  }

  // stage half h of pair p into buf[slot] using lanes [0, nlanes)
  auto stage = [&](int ph, int slot, int lane, int nlanes) {
    const int p = ph >> 1, h = ph & 1;
    const int c0 = 2 * (pg0 + p);
    const int row0 = h ? 79 : 0;
    const f4* __restrict__ srcA =
        (const f4*)(feat + ((size_t)b * FM_C + c0) * PLANE) + row0 * (FM_W / 4);
    const f4* __restrict__ srcB = srcA + PLANE4;
    uint4* __restrict__ pl4 = (uint4*)(&buf[slot][4]);
    for (int i = lane; i < PL_F4; i += nlanes) {
      const f4 a = srcA[i];
      const f4 bb = srcB[i];
      const __half2 h0 = __floats2half2_rn(a.x, bb.x);
      const __half2 h1 = __floats2half2_rn(a.y, bb.y);
      const __half2 h2 = __floats2half2_rn(a.z, bb.z);
      const __half2 h3 = __floats2half2_rn(a.w, bb.w);
      uint4 u;
      u.x = *(const unsigned*)&h0;
      u.y = *(const unsigned*)&h1;
      u.z = *(const unsigned*)&h2;
      u.w = *(const unsigned*)&h3;
      pl4[i] = u;
    }
  };

  auto consume = [&](int ph, int slot, int lane, int nlanes) {
    const int p = ph >> 1, h = ph & 1;
    const int c0 = 2 * (pg0 + p);
    const uint4* __restrict__ stream = samples + (h ? soffH1 : soffH0);
    const int n = h ? cntH1 : cntH0;
    const __half2* __restrict__ pb = buf[slot];
    float* __restrict__ outc = out + (size_t)c0 * OSP;
#pragma unroll 2
    for (int w = lane; w < n; w += nlanes) {
      const uint4 sd = stream[w];
      const int bxs = (int)(sd.x & 0x7FFFu);
      const int o10 = bxs + (int)((sd.x >> 15) & 1u) * FM_W;

      // adjacent-pair reads -> ds_read2_b32; each half2 = both channels
      const __half2 pL0 = pb[bxs];
      const __half2 pR0 = pb[bxs + 1];
      const __half2 pL1 = pb[o10];
      const __half2 pR1 = pb[o10 + 1];

      const __half2 ax = *(const __half2*)&sd.y;
      const __half2 axl = __half2half2(__low2half(ax));
      const __half2 axr = __half2half2(__high2half(ax));
      const __half2 hx0 = __hfma2(pR0, axr, __hmul2(pL0, axl));
      const __half2 hx1 = __hfma2(pR1, axr, __hmul2(pL1, axl));

      const float wy1 = (float)((sd.x >> 16) & 0x1FFFu) * (1.0f / 8192.0f);
      const float ay0 = ((sd.x >> 29) & 1u) ? (1.0f - wy1) : 0.0f;
      const float ay1 = ((sd.x >> 30) & 1u) ? wy1 : 0.0f;

      const float vA = ay0 * __low2float(hx0) + ay1 * __low2float(hx1);
      const float vB = ay0 * __high2float(hx0) + ay1 * __high2float(hx1);

      float* __restrict__ dst = outc + sd.z;
      dst[0] = vA;
      dst[OSP] = vB;
    }
  };

  // prologue: everyone stages phase 0 into slot 0
  stage(0, 0, t, MAIN_BLK);
  __syncthreads();

  for (int ph = 0; ph < NPHASE; ++ph) {
    const int slot = ph & 1;
    if (wave < NPROD) {
      if (ph + 1 < NPHASE) stage(ph + 1, slot ^ 1, t, NPROD * 64);
    } else {
      consume(ph, slot, t - NPROD * 64, (16 - NPROD) * 64);
    }
    __syncthreads();
  }
}

extern "C" void kernel_launch(void* const* d_in, const int* in_sizes, int n_in,
                              void* d_out, int out_size, void* d_ws, size_t ws_size,
                              hipStream_t stream) {
  const float* feat = (const float*)d_in[0];
  const float* rois = (const float*)d_in[1];
  float* out = (float*)d_out;
  int* ws = (int*)d_ws;
  uint4* samples = (uint4*)((char*)d_ws + WS_SAMPLES_BYTE_OFF);

  const int K = in_sizes[1] / 5;  // 1024
  const int total = K * OSP;

  setup_kernel<<<1, 1024, 0, stream>>>(rois, K, ws);
  precompute_kernel<<<(total + 255) / 256, 256, 0, stream>>>(rois, ws, total,
                                                             samples);
  roi_align_main_kernel<<<dim3(FM_C / 2 / NCP, FM_N), MAIN_BLK, 0, stream>>>(
      feat, ws, samples, out);
}

// Round 11
// 123.330 us; speedup vs baseline: 1.3076x; 1.0378x over previous
//
#include <hip/hip_runtime.h>
#include <hip/hip_fp16.h>

// RoI Align, ALIGNED=False, SCALE=160.
// feat: (8, 256, 160, 160) fp32; rois: (1024,5); out: (1024, 256, 14, 14) fp32
//
// R11: VMEM-read-free compute phases. Per phase: (1) prefetch this phase's
// descriptors into STATICALLY-INDEXED registers (TRIP=16 unrolled), (2) issue
// next phase's half-plane loads, (3) compiler fence, (4) compute touches only
// regs/LDS/stores -> plane loads stay in flight across compute (vmcnt FIFO:
// desc loads are older, counted wait releases them first). Double-buffered
// half-planes (2 x 51.9 KB) from R9's iy-monotonic split. 1 block/CU.

#define FM_N 8
#define FM_C 256
#define FM_H 160
#define FM_W 160
#define PLANE (FM_H * FM_W)     // 25600
#define PLANE4 (PLANE / 4)      // 6400
#define OH 14
#define OW 14
#define OSP (OH * OW)           // 196
#define KMAX 1024
#define SCALE_HW 160.0f
#define MAIN_BLK 1024
#define NCP 4                   // channel-pairs per block
#define NPHASE (2 * NCP)        // (pair, half) phases
#define ROWS 81                 // half-plane rows (1 overlap row)
#define PL_ENT (ROWS * FM_W)    // 12960
#define PL_F4 (PL_ENT / 4)      // 3240
#define TAILPAD 172             // boundary insurance (zeroed)
#define TRIP 16                 // static desc iters: covers cnt <= 16384

typedef float f4 __attribute__((ext_vector_type(4)));

// ws layout (int32 units):
//   [0..16)   cnt16[b*2+h]; [16..32) soff16; [32..32+3*KMAX) kinfo[k]
//   byte 12544:            desc[K*196]  as uint2 (8 B)
//   byte 12544+1605632:    oidx[K*196]  as uint  (4 B)
#define WS_KINFO_OFF 32
#define WS_DESC_BYTE_OFF 12544
#define WS_OIDX_BYTE_OFF (12544 + KMAX * OSP * 8)

// Shared between setup & precompute so the half-split test is bit-identical.
__device__ __forceinline__ float iy_of(float y1, float y2, int oy) {
  return fmaf((float)oy * (1.0f / (OH - 1)), y2 - y1, y1) - 0.5f;
}

__global__ __launch_bounds__(1024) void setup_kernel(
    const float* __restrict__ rois, int K, int* __restrict__ ws) {
  __shared__ int cnt[16];
  __shared__ int soff[16];
  const int t = threadIdx.x;
  if (t < 16) cnt[t] = 0;
  __syncthreads();
  int posA = 0, posB = 0, c0 = 0, b = 0;
  if (t < K) {
    b = (int)rois[t * 5];
    const float y1 = rois[t * 5 + 2] * SCALE_HW;
    const float y2 = rois[t * 5 + 4] * SCALE_HW;
#pragma unroll
    for (int oy = 0; oy < OH; ++oy)
      c0 += (iy_of(y1, y2, oy) < 80.0f) ? 1 : 0;   // monotonic in oy
    posA = atomicAdd(&cnt[b * 2 + 0], c0 * OW);
    posB = atomicAdd(&cnt[b * 2 + 1], (OH - c0) * OW);
  }
  __syncthreads();
  if (t == 0) {
    int acc = 0;
    for (int i = 0; i < 16; ++i) { soff[i] = acc; acc += cnt[i]; }
  }
  __syncthreads();
  if (t < 16) { ws[t] = cnt[t]; ws[16 + t] = soff[t]; }
  if (t < K) {
    ws[WS_KINFO_OFF + 3 * t + 0] = soff[b * 2 + 0] + posA;
    ws[WS_KINFO_OFF + 3 * t + 1] = soff[b * 2 + 1] + posB;
    ws[WS_KINFO_OFF + 3 * t + 2] = c0;
  }
}

__global__ __launch_bounds__(256) void precompute_kernel(
    const float* __restrict__ rois, const int* __restrict__ ws, int total,
    uint2* __restrict__ desc, unsigned* __restrict__ oidx) {
  const int g = blockIdx.x * 256 + threadIdx.x;
  if (g >= total) return;
  const int k = g / OSP;
  const int s = g - k * OSP;
  const int oy = s / OW;
  const int ox = s - oy * OW;

  const float x1 = rois[k * 5 + 1] * SCALE_HW;
  const float y1 = rois[k * 5 + 2] * SCALE_HW;
  const float x2 = rois[k * 5 + 3] * SCALE_HW;
  const float y2 = rois[k * 5 + 4] * SCALE_HW;

  // ALIGNED=False index math collapses to ix = fx - 0.5
  const float ix = fmaf((float)ox * (1.0f / (OW - 1)), x2 - x1, x1) - 0.5f;
  const float iy = iy_of(y1, y2, oy);

  const float fx0 = floorf(ix);
  const float fy0 = floorf(iy);
  const int x0 = (int)fx0;
  const int y0 = (int)fy0;
  const float wx1 = ix - fx0;
  const float wy1 = iy - fy0;

  const bool vx0 = (x0 >= 0 && x0 < FM_W);
  const bool vx1 = (x0 + 1 >= 0 && x0 + 1 < FM_W);
  const unsigned vy0 = (y0 >= 0 && y0 < FM_H) ? 1u : 0u;
  const unsigned vy1 = (y0 + 1 >= 0 && y0 + 1 < FM_H) ? 1u : 0u;

  const int x0c = min(max(x0, 0), FM_W - 1);
  const int x1c = min(max(x0 + 1, 0), FM_W - 1);
  const int y0c = min(max(y0, 0), FM_H - 1);
  const int y1c = min(max(y0 + 1, 0), FM_H - 1);

  const int o00 = y0c * FM_W + x0c;
  const int o01 = y0c * FM_W + x1c;
  // Left-base: corners are always {plane[bx], plane[bx+1]} (border cases
  // carry zero ax weight on the garbage side).
  const int bx = vx1 ? (o01 - 1) : o00;

  const int ca = ws[WS_KINFO_OFF + 3 * k + 0];
  const int cb = ws[WS_KINFO_OFF + 3 * k + 1];
  const int c0 = ws[WS_KINFO_OFF + 3 * k + 2];
  const int h = (oy >= c0) ? 1 : 0;              // == (iy >= 80) by monotonicity
  const int row0 = h ? 79 : 0;
  const unsigned bxs = (unsigned)(bx - row0 * FM_W + 4);  // local + front pad
  const unsigned dyr = (unsigned)(y1c - y0c);    // 0/1
  unsigned wq = (unsigned)(wy1 * 8192.0f + 0.5f);
  wq = wq > 8191u ? 8191u : wq;

  const __half2 axh = __floats2half2_rn((1.0f - wx1) * (vx0 ? 1.0f : 0.0f),
                                        wx1 * (vx1 ? 1.0f : 0.0f));
  uint2 sd;
  sd.x = bxs | (dyr << 15) | (wq << 16) | (vy0 << 29) | (vy1 << 30);
  sd.y = *(const unsigned*)&axh;

  const int pos = h ? (cb + (oy - c0) * OW + ox) : (ca + oy * OW + ox);
  desc[pos] = sd;
  oidx[pos] = (unsigned)(k * (FM_C * OSP) + s);  // + c*OSP at store time
}

__global__ __launch_bounds__(MAIN_BLK) void roi_align_main_kernel(
    const float* __restrict__ feat, const int* __restrict__ ws,
    const uint2* __restrict__ desc, const unsigned* __restrict__ oidx,
    float* __restrict__ out, int total) {
  // Double-buffered half-plane: [4 front pad][81x160 half2][zero tail pad].
  __shared__ __align__(16) __half2 buf[2][4 + PL_ENT + TAILPAD];  // ~105 KB

  const int b = blockIdx.y;
  const int pg0 = blockIdx.x * NCP;
  const int t = threadIdx.x;

  const int cntA = ws[b * 2 + 0], cntB = ws[b * 2 + 1];
  const int soffA = ws[16 + b * 2 + 0], soffB = ws[16 + b * 2 + 1];

  const __half2 hz = __floats2half2_rn(0.0f, 0.0f);
  if (t < 4) { buf[0][t] = hz; buf[1][t] = hz; }
  if (t < TAILPAD) {
    buf[0][4 + PL_ENT + t] = hz;
    buf[1][4 + PL_ENT + t] = hz;
  }

  f4 ra[4], rb[4];

  // issue half-plane loads for phase ph into ra/rb (clamped -> unguarded)
  auto load_plane = [&](int ph) {
    const int p = ph >> 1, h = ph & 1;
    const int c0 = 2 * (pg0 + p);
    const int row0 = h ? 79 : 0;
    const f4* __restrict__ srcA =
        (const f4*)(feat + ((size_t)b * FM_C + c0) * PLANE) + row0 * (FM_W / 4);
    const f4* __restrict__ srcB = srcA + PLANE4;
#pragma unroll
    for (int i = 0; i < 4; ++i) {
      const int idx = min(t + i * MAIN_BLK, PL_F4 - 1);
      ra[i] = srcA[idx];
      rb[i] = srcB[idx];
    }
  };

  auto write_plane = [&](int slot) {
    uint4* __restrict__ pl4 = (uint4*)(&buf[slot][4]);
#pragma unroll
    for (int i = 0; i < 4; ++i) {
      const int idx = min(t + i * MAIN_BLK, PL_F4 - 1);  // dup writes benign
      const __half2 h0 = __floats2half2_rn(ra[i].x, rb[i].x);
      const __half2 h1 = __floats2half2_rn(ra[i].y, rb[i].y);
      const __half2 h2 = __floats2half2_rn(ra[i].z, rb[i].z);
      const __half2 h3 = __floats2half2_rn(ra[i].w, rb[i].w);
      uint4 u;
      u.x = *(const unsigned*)&h0;
      u.y = *(const unsigned*)&h1;
      u.z = *(const unsigned*)&h2;
      u.w = *(const unsigned*)&h3;
      pl4[idx] = u;
    }
  };

  // prologue: stage phase 0 into buf[0]
  load_plane(0);
  write_plane(0);
  __syncthreads();

  for (int ph = 0; ph < NPHASE; ++ph) {
    const int p = ph >> 1, h = ph & 1, slot = ph & 1;
    const int cnt = h ? cntB : cntA;
    const int sbase = min(h ? soffB : soffA, total - 1);
    const int cmax = max(cnt, 1) - 1;

    // 1. descriptor prefetch for THIS phase (oldest in vmcnt FIFO)
    uint2 d[TRIP];
    unsigned ov[TRIP];
#pragma unroll
    for (int i = 0; i < TRIP; ++i) {
      const int idx = min(t + i * MAIN_BLK, cmax);
      d[i] = desc[sbase + idx];
      ov[i] = oidx[sbase + idx];
    }
    // 2. next phase's plane loads (stay in flight across compute)
    if (ph + 1 < NPHASE) load_plane(ph + 1);
    // 3. compiler fence: loads above cannot sink below (IR-level)
    asm volatile("" ::: "memory");

    // 4. compute: regs + LDS + stores only — zero VMEM reads
    const int c0 = 2 * (pg0 + p);
    float* __restrict__ outc = out + (size_t)c0 * OSP;
    const __half2* __restrict__ pb = buf[slot];
#pragma unroll
    for (int i = 0; i < TRIP; ++i) {
      const int idx = t + i * MAIN_BLK;
      if (idx < cnt) {
        const uint2 sd = d[i];
        const int bxs = (int)(sd.x & 0x7FFFu);
        const int o10 = bxs + (int)((sd.x >> 15) & 1u) * FM_W;

        const __half2 pL0 = pb[bxs];
        const __half2 pR0 = pb[bxs + 1];
        const __half2 pL1 = pb[o10];
        const __half2 pR1 = pb[o10 + 1];

        const __half2 ax = *(const __half2*)&sd.y;
        const __half2 axl = __half2half2(__low2half(ax));
        const __half2 axr = __half2half2(__high2half(ax));
        const __half2 hx0 = __hfma2(pR0, axr, __hmul2(pL0, axl));
        const __half2 hx1 = __hfma2(pR1, axr, __hmul2(pL1, axl));

        const float wy1 = (float)((sd.x >> 16) & 0x1FFFu) * (1.0f / 8192.0f);
        const float ay0 = ((sd.x >> 29) & 1u) ? (1.0f - wy1) : 0.0f;
        const float ay1 = ((sd.x >> 30) & 1u) ? wy1 : 0.0f;

        const float vA = ay0 * __low2float(hx0) + ay1 * __low2float(hx1);
        const float vB = ay0 * __high2float(hx0) + ay1 * __high2float(hx1);

        float* __restrict__ dst = outc + ov[i];
        dst[0] = vA;
        dst[OSP] = vB;
      }
    }
    // overflow epilogue (pathological inputs only; cnt <= 16384 in practice)
    for (int w = TRIP * MAIN_BLK + t; w < cnt; w += MAIN_BLK) {
      const uint2 sd = desc[sbase + w];
      const unsigned o = oidx[sbase + w];
      const int bxs = (int)(sd.x & 0x7FFFu);
      const int o10 = bxs + (int)((sd.x >> 15) & 1u) * FM_W;
      const __half2 pL0 = pb[bxs], pR0 = pb[bxs + 1];
      const __half2 pL1 = pb[o10], pR1 = pb[o10 + 1];
      const __half2 ax = *(const __half2*)&sd.y;
      const __half2 axl = __half2half2(__low2half(ax));
      const __half2 axr = __half2half2(__high2half(ax));
      const __half2 hx0 = __hfma2(pR0, axr, __hmul2(pL0, axl));
      const __half2 hx1 = __hfma2(pR1, axr, __hmul2(pL1, axl));
      const float wy1 = (float)((sd.x >> 16) & 0x1FFFu) * (1.0f / 8192.0f);
      const float ay0 = ((sd.x >> 29) & 1u) ? (1.0f - wy1) : 0.0f;
      const float ay1 = ((sd.x >> 30) & 1u) ? wy1 : 0.0f;
      float* __restrict__ dst = outc + o;
      dst[0] = ay0 * __low2float(hx0) + ay1 * __low2float(hx1);
      dst[OSP] = ay0 * __high2float(hx0) + ay1 * __high2float(hx1);
    }

    // 5. unpack the (now landed) plane into the other buffer
    if (ph + 1 < NPHASE) write_plane(slot ^ 1);
    __syncthreads();
  }
}

extern "C" void kernel_launch(void* const* d_in, const int* in_sizes, int n_in,
                              void* d_out, int out_size, void* d_ws, size_t ws_size,
                              hipStream_t stream) {
  const float* feat = (const float*)d_in[0];
  const float* rois = (const float*)d_in[1];
  float* out = (float*)d_out;
  int* ws = (int*)d_ws;
  uint2* desc = (uint2*)((char*)d_ws + WS_DESC_BYTE_OFF);
  unsigned* oidx = (unsigned*)((char*)d_ws + WS_OIDX_BYTE_OFF);

  const int K = in_sizes[1] / 5;  // 1024
  const int total = K * OSP;

  setup_kernel<<<1, 1024, 0, stream>>>(rois, K, ws);
  precompute_kernel<<<(total + 255) / 256, 256, 0, stream>>>(rois, ws, total,
                                                             desc, oidx);
  roi_align_main_kernel<<<dim3(FM_C / 2 / NCP, FM_N), MAIN_BLK, 0, stream>>>(
      feat, ws, desc, oidx, out, total);
}

// Round 12
// 121.173 us; speedup vs baseline: 1.3309x; 1.0178x over previous
//
#include <hip/hip_runtime.h>
#include <hip/hip_fp16.h>

// RoI Align, ALIGNED=False, SCALE=160.
// feat: (8, 256, 160, 160) fp32; rois: (1024,5); out: (1024, 256, 14, 14) fp32
//
// R12 = the proven 98.7 µs structure (R5-proposal) + bank-conflict fix:
// LDS plane row stride padded 160 -> 164 half2 entries (164 % 32 = 4, so each
// feature row rotates its bank base by 4; stride 160 ≡ 0 mod 32 made all rows
// bank-aligned -> ~5-way systematic conflicts, 7.6M cycles/dispatch).
// Row = 41 uint4 (16B-aligned staging preserved). Pad columns zeroed once.
//
//  A) setup_kernel: per-batch counts, batch-grouped klist.
//  B) precompute_kernel: 8-byte descriptor per (k,s): left-base bx in the
//     STRIDE-164 coordinate system (corners always {plane[bx], plane[bx+1]},
//     border cases folded into zero ax weights), dyr, wy1 q13, vy bits,
//     ax as half2. Weights computed once, not 256x.
//  C) main kernel: block = (b, 2 channel-PAIRS); planes staged interleaved as
//     half2 (one ds_read2_b32 serves 2 channels x 2 corners); serial
//     stage -> compute (overlap schemes R4-R11 all regressed; vmcnt FIFO +
//     lockstep co-residency make them structurally ineffective here).

#define FM_N 8
#define FM_C 256
#define FM_H 160
#define FM_W 160
#define PLANE (FM_H * FM_W)     // 25600
#define PLANE4 (PLANE / 4)      // 6400
#define LDSW 164                // padded row stride (entries); 164 % 32 = 4
#define LROW4 (LDSW / 4)        // 41 uint4 per row
#define PL_ENT (FM_H * LDSW)    // 26240
#define OH 14
#define OW 14
#define OSP (OH * OW)           // 196
#define KMAX 1024
#define SCALE_HW 160.0f
#define MAIN_BLK 1024
#define NCP 2                   // channel-pairs per block (4 channels)
#define FRONTPAD 4
#define TAILPAD 8

typedef float f4 __attribute__((ext_vector_type(4)));

// ws layout (int32 units):
//   [0..7]      cnt[b]
//   [8..15]     koff[b] (exclusive prefix sum)
//   [16..16+KMAX) klist[slot] -> k (batch-grouped)
//   byte 4224:  samples[K*196] as uint2
#define WS_KLIST_OFF 16
#define WS_SAMPLES_BYTE_OFF 4224

__global__ void setup_kernel(const float* __restrict__ rois, int K,
                             int* __restrict__ ws) {
  __shared__ int cnt[FM_N];
  __shared__ int koff[FM_N];
  const int t = threadIdx.x;
  if (t < FM_N) cnt[t] = 0;
  __syncthreads();
  int myb = -1, pos = 0;
  if (t < K) {
    myb = (int)rois[t * 5];
    pos = atomicAdd(&cnt[myb], 1);  // rank order irrelevant: each sample
                                    // writes a unique output location
  }
  __syncthreads();
  if (t == 0) {
    int acc = 0;
    for (int b = 0; b < FM_N; ++b) { koff[b] = acc; acc += cnt[b]; }
  }
  __syncthreads();
  if (t < K) ws[WS_KLIST_OFF + koff[myb] + pos] = t;
  if (t < FM_N) { ws[t] = cnt[t]; ws[FM_N + t] = koff[t]; }
}

__global__ __launch_bounds__(256) void precompute_kernel(
    const float* __restrict__ rois, const int* __restrict__ ws, int K,
    uint2* __restrict__ samples) {
  const int g = blockIdx.x * 256 + threadIdx.x;
  if (g >= K * OSP) return;
  const int slot = g / OSP;            // batch-grouped slot
  const int s = g - slot * OSP;
  const int k = ws[WS_KLIST_OFF + slot];

  const float x1 = rois[k * 5 + 1] * SCALE_HW;
  const float y1 = rois[k * 5 + 2] * SCALE_HW;
  const float x2 = rois[k * 5 + 3] * SCALE_HW;
  const float y2 = rois[k * 5 + 4] * SCALE_HW;

  const int oy = s / OW;
  const int ox = s - oy * OW;
  const float gx = (float)ox * (1.0f / (OW - 1));
  const float gy = (float)oy * (1.0f / (OH - 1));

  // ALIGNED=False index math collapses to ix = fx - 0.5
  const float ix = x1 + gx * (x2 - x1) - 0.5f;
  const float iy = y1 + gy * (y2 - y1) - 0.5f;

  const float fx0 = floorf(ix);
  const float fy0 = floorf(iy);
  const int x0 = (int)fx0;
  const int y0 = (int)fy0;
  const float wx1 = ix - fx0;
  const float wy1 = iy - fy0;

  const bool vx0 = (x0 >= 0 && x0 < FM_W);
  const bool vx1 = (x0 + 1 >= 0 && x0 + 1 < FM_W);
  const unsigned vy0 = (y0 >= 0 && y0 < FM_H) ? 1u : 0u;
  const unsigned vy1 = (y0 + 1 >= 0 && y0 + 1 < FM_H) ? 1u : 0u;

  const int x0c = min(max(x0, 0), FM_W - 1);
  const int x1c = min(max(x0 + 1, 0), FM_W - 1);
  const int y0c = min(max(y0, 0), FM_H - 1);
  const int y1c = min(max(y0 + 1, 0), FM_H - 1);

  // Stride-164 LDS coordinates.
  const int o00 = y0c * LDSW + x0c;
  const int o01 = y0c * LDSW + x1c;
  // Left-base: corners are always {plane[bx], plane[bx+1]}; border cases
  // carry zero ax weight on the garbage side (pads zeroed in main kernel).
  const int bx = vx1 ? (o01 - 1) : o00;           // [-1, 26235]
  const unsigned bxs = (unsigned)(bx + FRONTPAD); // 15 bits (max 26239)
  const unsigned dyr = (unsigned)(y1c - y0c);     // 0/1
  unsigned wq = (unsigned)(wy1 * 8192.0f + 0.5f);
  wq = wq > 8191u ? 8191u : wq;

  const __half2 axh = __floats2half2_rn((1.0f - wx1) * (vx0 ? 1.0f : 0.0f),
                                        wx1 * (vx1 ? 1.0f : 0.0f));
  uint2 sd;
  sd.x = bxs | (dyr << 15) | (wq << 16) | (vy0 << 29) | (vy1 << 30);
  sd.y = *(const unsigned*)&axh;
  samples[(size_t)slot * OSP + s] = sd;
}

__global__ __launch_bounds__(MAIN_BLK) void roi_align_main_kernel(
    const float* __restrict__ feat, const int* __restrict__ ws,
    const uint2* __restrict__ samples, float* __restrict__ out) {
  // [FRONTPAD][160 rows x 164 entries (last 4 per row = zeroed pad)][TAILPAD]
  __shared__ __align__(16) __half2 planeBuf[FRONTPAD + PL_ENT + TAILPAD];
  __shared__ int klist[KMAX];  // precomputed k*FM_C*OSP output bases

  const int b = blockIdx.y;
  const int p0 = blockIdx.x * NCP;  // first channel-pair index
  const int t = threadIdx.x;

  const int cnt = ws[b];
  const int koff = ws[FM_N + b];
  for (int i = t; i < cnt; i += MAIN_BLK)
    klist[i] = ws[WS_KLIST_OFF + koff + i] * (FM_C * OSP);

  // zero front pad, tail pad, and the 4 pad columns of every row (once)
  const __half2 hz = __floats2half2_rn(0.0f, 0.0f);
  if (t < FRONTPAD) planeBuf[t] = hz;
  if (t < TAILPAD) planeBuf[FRONTPAD + PL_ENT + t] = hz;
  if (t < FM_H * 4) {
    const int y = t >> 2;
    planeBuf[FRONTPAD + y * LDSW + FM_W + (t & 3)] = hz;
  }

  const uint2* __restrict__ sam = samples + (size_t)koff * OSP;
  const int total = cnt * OSP;

  for (int cp = 0; cp < NCP; ++cp) {
    const int c0 = 2 * (p0 + cp);
    if (cp) __syncthreads();  // previous phase's readers done

    // ---- stage planes c0, c0+1 interleaved as half2, stride-164 rows
    const f4* __restrict__ srcA =
        (const f4*)(feat + ((size_t)b * FM_C + c0) * PLANE);
    const f4* __restrict__ srcB = srcA + PLANE4;
    uint4* __restrict__ pl4 = (uint4*)(planeBuf + FRONTPAD);  // 16B-aligned
    for (int i = t; i < PLANE4; i += MAIN_BLK) {
      const f4 a = srcA[i];
      const f4 bb = srcB[i];
      const int y = i / (FM_W / 4);          // feature row
      const int j = i - y * (FM_W / 4);      // uint4 chunk within row
      const __half2 h0 = __floats2half2_rn(a.x, bb.x);
      const __half2 h1 = __floats2half2_rn(a.y, bb.y);
      const __half2 h2 = __floats2half2_rn(a.z, bb.z);
      const __half2 h3 = __floats2half2_rn(a.w, bb.w);
      uint4 u;
      u.x = *(const unsigned*)&h0;
      u.y = *(const unsigned*)&h1;
      u.z = *(const unsigned*)&h2;
      u.w = *(const unsigned*)&h3;
      pl4[y * LROW4 + j] = u;
    }
    __syncthreads();

    // ---- gather all samples of batch b for channels c0, c0+1
    float* __restrict__ outc = out + (size_t)c0 * OSP;
#pragma unroll 4
    for (int w = t; w < total; w += MAIN_BLK) {
      const uint2 sd = sam[w];
      const unsigned kl = (unsigned)w / OSP;  // magic-mul div
      const int s = w - (int)kl * OSP;
      const int kbase = klist[kl];

      const int bxs = (int)(sd.x & 0x7FFFu);
      const int o10 = bxs + (int)((sd.x >> 15) & 1u) * LDSW;

      // adjacent-pair reads -> ds_read2_b32; each half2 = both channels
      const __half2 pL0 = planeBuf[bxs];
      const __half2 pR0 = planeBuf[bxs + 1];
      const __half2 pL1 = planeBuf[o10];
      const __half2 pR1 = planeBuf[o10 + 1];

      const __half2 ax = *(const __half2*)&sd.y;
      const __half2 axl = __half2half2(__low2half(ax));
      const __half2 axr = __half2half2(__high2half(ax));
      const __half2 hx0 = __hfma2(pR0, axr, __hmul2(pL0, axl));
      const __half2 hx1 = __hfma2(pR1, axr, __hmul2(pL1, axl));

      const float wy1 = (float)((sd.x >> 16) & 0x1FFFu) * (1.0f / 8192.0f);
      const float ay0 = ((sd.x >> 29) & 1u) ? (1.0f - wy1) : 0.0f;
      const float ay1 = ((sd.x >> 30) & 1u) ? wy1 : 0.0f;

      const float vA = ay0 * __low2float(hx0) + ay1 * __low2float(hx1);
      const float vB = ay0 * __high2float(hx0) + ay1 * __high2float(hx1);

      const size_t ob = (size_t)(kbase + s);
      outc[ob] = vA;
      outc[ob + OSP] = vB;
    }
  }
}

extern "C" void kernel_launch(void* const* d_in, const int* in_sizes, int n_in,
                              void* d_out, int out_size, void* d_ws, size_t ws_size,
                              hipStream_t stream) {
  const float* feat = (const float*)d_in[0];
  const float* rois = (const float*)d_in[1];
  float* out = (float*)d_out;
  int* ws = (int*)d_ws;
  uint2* samples = (uint2*)((char*)d_ws + WS_SAMPLES_BYTE_OFF);

  const int K = in_sizes[1] / 5;  // 1024

  setup_kernel<<<1, 1024, 0, stream>>>(rois, K, ws);
  precompute_kernel<<<(K * OSP + 255) / 256, 256, 0, stream>>>(rois, ws, K,
                                                               samples);
  roi_align_main_kernel<<<dim3(FM_C / 2 / NCP, FM_N), MAIN_BLK, 0, stream>>>(
      feat, ws, samples, out);
}

// Round 13
// 98.270 us; speedup vs baseline: 1.6411x; 1.2331x over previous
//
#include <hip/hip_runtime.h>
#include <hip/hip_fp16.h>

// RoI Align, ALIGNED=False, SCALE=160.
// feat: (8, 256, 160, 160) fp32; rois: (1024,5); out: (1024, 256, 14, 14) fp32
//
// R13 = EXACT Round-6 champion (98.7 µs: NT staging loads, NCP=2,
// load_pair/write_plane split, ds_read2-pair + hfma2 gather) with ONE change:
// LDS row stride 160 -> 164 half2 (164 % 32 = 4 rotates each feature row's
// bank base by 4; stride 160 made all rows bank-aligned -> measured 7.6M
// conflict cycles, pad measured 4.76M in R12). R12's wall regression is
// attributed to its dropped nontemporal loads (L2 pollution by the ~100 MB
// staging stream), not the pad — this round isolates that.

#define FM_N 8
#define FM_C 256
#define FM_H 160
#define FM_W 160
#define PLANE (FM_H * FM_W)   // 25600
#define PLANE4 (PLANE / 4)    // 6400 float4 per plane
#define LDSW 164              // padded LDS row stride (half2 entries)
#define LROW4 (LDSW / 4)      // 41 uint4 per row
#define PL_ENT (FM_H * LDSW)  // 26240
#define OH 14
#define OW 14
#define OSP (OH * OW)         // 196
#define KMAX 1024
#define SCALE_HW 160.0f
#define MAIN_BLK 1024
#define NCP 2                 // channel-pairs per block (4 channels)
#define STG_IT 7              // ceil(PLANE4 / MAIN_BLK)

typedef float f4 __attribute__((ext_vector_type(4)));

// ws layout (int32 units):
//   [0..7]      cnt[b]
//   [8..15]     koff[b] (exclusive prefix sum)
//   [16..16+KMAX) klist[slot] -> k   (batch-grouped)
//   byte 4224:  samples[K*196] as uint2
#define WS_KLIST_OFF 16
#define WS_SAMPLES_BYTE_OFF 4224

__global__ void setup_kernel(const float* __restrict__ rois, int K,
                             int* __restrict__ ws) {
  __shared__ int cnt[FM_N];
  __shared__ int koff[FM_N];
  const int t = threadIdx.x;
  if (t < FM_N) cnt[t] = 0;
  __syncthreads();
  int myb = -1, pos = 0;
  if (t < K) {
    myb = (int)rois[t * 5];
    pos = atomicAdd(&cnt[myb], 1);  // rank order irrelevant: each sample
                                    // writes a unique output location
  }
  __syncthreads();
  if (t == 0) {
    int acc = 0;
    for (int b = 0; b < FM_N; ++b) { koff[b] = acc; acc += cnt[b]; }
  }
  __syncthreads();
  if (t < K) ws[WS_KLIST_OFF + koff[myb] + pos] = t;
  if (t < FM_N) { ws[t] = cnt[t]; ws[FM_N + t] = koff[t]; }
}

__global__ __launch_bounds__(256) void precompute_kernel(
    const float* __restrict__ rois, const int* __restrict__ ws, int K,
    uint2* __restrict__ samples) {
  const int g = blockIdx.x * 256 + threadIdx.x;
  if (g >= K * OSP) return;
  const int slot = g / OSP;            // batch-grouped slot
  const int s = g - slot * OSP;
  const int k = ws[WS_KLIST_OFF + slot];

  const float x1 = rois[k * 5 + 1] * SCALE_HW;
  const float y1 = rois[k * 5 + 2] * SCALE_HW;
  const float x2 = rois[k * 5 + 3] * SCALE_HW;
  const float y2 = rois[k * 5 + 4] * SCALE_HW;

  const int oy = s / OW;
  const int ox = s - oy * OW;
  const float gx = (float)ox * (1.0f / (OW - 1));
  const float gy = (float)oy * (1.0f / (OH - 1));

  // ALIGNED=False index math collapses to ix = fx - 0.5
  const float ix = x1 + gx * (x2 - x1) - 0.5f;
  const float iy = y1 + gy * (y2 - y1) - 0.5f;

  const float fx0 = floorf(ix);
  const float fy0 = floorf(iy);
  const int x0 = (int)fx0;
  const int y0 = (int)fy0;
  const float wx1 = ix - fx0;
  const float wy1 = iy - fy0;

  const bool vx0 = (x0 >= 0 && x0 < FM_W);
  const bool vx1 = (x0 + 1 >= 0 && x0 + 1 < FM_W);
  const unsigned vy0 = (y0 >= 0 && y0 < FM_H) ? 1u : 0u;
  const unsigned vy1 = (y0 + 1 >= 0 && y0 + 1 < FM_H) ? 1u : 0u;

  const int x0c = min(max(x0, 0), FM_W - 1);
  const int x1c = min(max(x0 + 1, 0), FM_W - 1);
  const int y0c = min(max(y0, 0), FM_H - 1);
  const int y1c = min(max(y0 + 1, 0), FM_H - 1);

  // Stride-164 LDS coordinates.
  const int o00 = y0c * LDSW + x0c;
  const int o01 = y0c * LDSW + x1c;
  // Left-base: corners are always {plane[bx], plane[bx+1]}; border cases
  // carry zero ax weight on the garbage side (pads zeroed in main kernel).
  const int bx = vx1 ? (o01 - 1) : o00;     // [-1, 26235]
  const unsigned bxs = (unsigned)(bx + 4);  // + front pad; 15 bits (<= 26239)
  const unsigned dyr = (unsigned)(y1c - y0c);  // 0/1
  unsigned wq = (unsigned)(wy1 * 8192.0f + 0.5f);
  wq = wq > 8191u ? 8191u : wq;

  const __half2 axh = __floats2half2_rn((1.0f - wx1) * (vx0 ? 1.0f : 0.0f),
                                        wx1 * (vx1 ? 1.0f : 0.0f));

  uint2 sd;
  sd.x = bxs | (dyr << 15) | (wq << 16) | (vy0 << 29) | (vy1 << 30);
  sd.y = *(const unsigned*)&axh;
  samples[(size_t)slot * OSP + s] = sd;
}

__global__ __launch_bounds__(MAIN_BLK) void roi_align_main_kernel(
    const float* __restrict__ feat, const int* __restrict__ ws,
    const uint2* __restrict__ samples, float* __restrict__ out) {
  // [4 front pad][160 rows x 164 entries (last 4/row zeroed)][8 tail pad]
  __shared__ __align__(16) __half2 planeBuf[4 + PL_ENT + 8];
  __shared__ int klist[KMAX];  // precomputed k*FM_C*OSP output bases

  const int b = blockIdx.y;
  const int p0 = blockIdx.x * NCP;  // first channel-pair index
  const int t = threadIdx.x;

  const int cnt = ws[b];
  const int koff = ws[FM_N + b];
  for (int i = t; i < cnt; i += MAIN_BLK)
    klist[i] = ws[WS_KLIST_OFF + koff + i] * (FM_C * OSP);
  const __half2 hz = __floats2half2_rn(0.0f, 0.0f);
  if (t < 4) planeBuf[t] = hz;
  if (t < 8) planeBuf[4 + PL_ENT + t] = hz;
  if (t < FM_H * 4) {  // zero the 4 pad columns of every row (once)
    const int y = t >> 2;
    planeBuf[4 + y * LDSW + FM_W + (t & 3)] = hz;
  }

  const uint2* __restrict__ sam = samples + (size_t)koff * OSP;
  const int total = cnt * OSP;
  const f4* __restrict__ fbase = (const f4*)feat + (size_t)b * FM_C * PLANE4;
  __half2* __restrict__ planeP = planeBuf + 4;

  f4 ra[STG_IT], rb[STG_IT];

  // issue NONTEMPORAL global loads for pair p into ra/rb (streaming data:
  // keep it out of L2 so descriptors/stores stay cached — R12 lesson)
  auto load_pair = [&](int p) {
    const f4* __restrict__ srcA = fbase + (size_t)(2 * p) * PLANE4;
    const f4* __restrict__ srcB = srcA + PLANE4;
#pragma unroll
    for (int i = 0; i < STG_IT; ++i) {
      const int idx = t + i * MAIN_BLK;
      if (idx < PLANE4) {
        ra[i] = __builtin_nontemporal_load(&srcA[idx]);
        rb[i] = __builtin_nontemporal_load(&srcB[idx]);
      }
    }
  };

  // convert staged regs to interleaved half2, write LDS at stride-164 rows
  auto write_plane = [&]() {
    uint4* __restrict__ pl4 = (uint4*)planeP;  // 16B-aligned
#pragma unroll
    for (int i = 0; i < STG_IT; ++i) {
      const int idx = t + i * MAIN_BLK;
      if (idx < PLANE4) {
        const int y = (int)((unsigned)idx / (FM_W / 4));   // feature row
        const int j = idx - y * (FM_W / 4);                // chunk in row
        const __half2 h0 = __floats2half2_rn(ra[i].x, rb[i].x);
        const __half2 h1 = __floats2half2_rn(ra[i].y, rb[i].y);
        const __half2 h2 = __floats2half2_rn(ra[i].z, rb[i].z);
        const __half2 h3 = __floats2half2_rn(ra[i].w, rb[i].w);
        uint4 u;
        u.x = *(const unsigned*)&h0;
        u.y = *(const unsigned*)&h1;
        u.z = *(const unsigned*)&h2;
        u.w = *(const unsigned*)&h3;
        pl4[y * LROW4 + j] = u;
      }
    }
  };

  auto compute_pair = [&](int c0) {
    float* __restrict__ outc = out + (size_t)c0 * OSP;
#pragma unroll 4
    for (int w = t; w < total; w += MAIN_BLK) {
      const uint2 sd = sam[w];
      const unsigned kl = (unsigned)w / OSP;  // magic-mul div
      const int s = w - (int)kl * OSP;
      const int kbase = klist[kl];

      const int bxs = (int)(sd.x & 0x7FFFu);
      const int o10 = bxs + (int)((sd.x >> 15) & 1u) * LDSW;

      // adjacent-pair LDS reads -> ds_read2_b32 (2 instrs for 4 corners,
      // each __half2 carries both channels)
      const __half2 pL0 = planeP[bxs - 4];   // == planeBuf[bxs]
      const __half2 pR0 = planeP[bxs - 3];
      const __half2 pL1 = planeP[o10 - 4];
      const __half2 pR1 = planeP[o10 - 3];

      const __half2 ax = *(const __half2*)&sd.y;
      const __half2 axl = __half2half2(__low2half(ax));
      const __half2 axr = __half2half2(__high2half(ax));
      const __half2 hx0 = __hfma2(pR0, axr, __hmul2(pL0, axl));
      const __half2 hx1 = __hfma2(pR1, axr, __hmul2(pL1, axl));

      const float wy1 = (float)((sd.x >> 16) & 0x1FFFu) * (1.0f / 8192.0f);
      const float ay0 = ((sd.x >> 29) & 1u) ? (1.0f - wy1) : 0.0f;
      const float ay1 = ((sd.x >> 30) & 1u) ? wy1 : 0.0f;

      const float vA = ay0 * __low2float(hx0) + ay1 * __low2float(hx1);
      const float vB = ay0 * __high2float(hx0) + ay1 * __high2float(hx1);

      const size_t ob = (size_t)(kbase + s);
      outc[ob] = vA;
      outc[ob + OSP] = vB;
    }
  };

  // prologue: stage pair p0
  load_pair(p0);
  write_plane();
  __syncthreads();

  for (int cp = 0; cp < NCP; ++cp) {
    if (cp + 1 < NCP) load_pair(p0 + cp + 1);  // in flight during compute
    compute_pair(2 * (p0 + cp));
    if (cp + 1 < NCP) {
      __syncthreads();   // everyone done reading current plane
      write_plane();     // vmcnt wait lands here, after compute
      __syncthreads();   // new plane visible
    }
  }
}

extern "C" void kernel_launch(void* const* d_in, const int* in_sizes, int n_in,
                              void* d_out, int out_size, void* d_ws, size_t ws_size,
                              hipStream_t stream) {
  const float* feat = (const float*)d_in[0];
  const float* rois = (const float*)d_in[1];
  float* out = (float*)d_out;
  int* ws = (int*)d_ws;
  uint2* samples = (uint2*)((char*)d_ws + WS_SAMPLES_BYTE_OFF);

  const int K = in_sizes[1] / 5;  // 1024

  setup_kernel<<<1, 1024, 0, stream>>>(rois, K, ws);
  precompute_kernel<<<(K * OSP + 255) / 256, 256, 0, stream>>>(rois, ws, K,
                                                               samples);
  roi_align_main_kernel<<<dim3(FM_C / 2 / NCP, FM_N), MAIN_BLK, 0, stream>>>(
      feat, ws, samples, out);
}

// Round 14
// 91.355 us; speedup vs baseline: 1.7653x; 1.0757x over previous
//
#include <hip/hip_runtime.h>
#include <hip/hip_fp16.h>

// RoI Align, ALIGNED=False, SCALE=160.
// feat: (8, 256, 160, 160) fp32; rois: (1024,5); out: (1024, 256, 14, 14) fp32
//
// R14 = R13 champion (NT staging, stride-164 pad, ds-pair gathers) evolved to
// FOUR channels per LDS pixel (half2x2, 8 B/px) via the R9 half-plane split
// (81 rows x 164 px x 8 B ~= 104 KB). Halves inner-loop iterations: one 16 B
// descriptor + 2 merged ds_read2_b64 + one weight-decode serve 4 channels.
// R9's ordered chunk streams (iy monotonic in oy -> rows [0,c0) half0,
// [c0,14) half1) keep stores coalesced; per-sample outidx keeps output
// deterministic. NT loads retained (R12/R13 isolation: worth ~22 µs).
//
//  1) setup_kernel (1 block): c0[k], per-(b,h) stream sizes, per-k chunk offs.
//  2) precompute_kernel: uint4 descriptor per (k,s) at its chunk slot:
//     {bx_local|dyr|wq13|vy0|vy1, ax(half2), outidx, 0}.
//  3) main: block=(quad q, b, h): zero pads; NT-stage 4 planes' 81 rows as
//     half2x2; gather stream; 4 stores/sample.

#define FM_N 8
#define FM_C 256
#define FM_H 160
#define FM_W 160
#define PLANE (FM_H * FM_W)     // 25600
#define PLANE4 (PLANE / 4)      // 6400
#define OH 14
#define OW 14
#define OSP (OH * OW)           // 196
#define KMAX 1024
#define SCALE_HW 160.0f
#define MAIN_BLK 1024
#define ROWS 81                 // half-plane rows (1 overlap row)
#define LDSW 164                // padded row stride in PIXELS (164%32=4)
#define ROW_F4 (FM_W / 4)       // 40 f4 chunks per source row
#define PL_PIX (ROWS * LDSW)    // 13284 pixels
#define PL_F4 (ROWS * ROW_F4)   // 3240 f4 chunks per plane half
#define FRONTPAD 2              // pixels (16 B, keeps rows 16B-aligned)
#define TAILPAD 6

typedef float f4 __attribute__((ext_vector_type(4)));

// ws layout (int32 units):
//   [0..16)   cnt16[b*2+h]; [16..32) soff16; [32..32+3*KMAX) kinfo[k]
//   byte 12544: samples[K*196] as uint4
#define WS_KINFO_OFF 32
#define WS_SAMPLES_BYTE_OFF 12544

// Shared between setup & precompute so the half-split test is bit-identical.
__device__ __forceinline__ float iy_of(float y1, float y2, int oy) {
  return fmaf((float)oy * (1.0f / (OH - 1)), y2 - y1, y1) - 0.5f;
}

__global__ __launch_bounds__(1024) void setup_kernel(
    const float* __restrict__ rois, int K, int* __restrict__ ws) {
  __shared__ int cnt[16];
  __shared__ int soff[16];
  const int t = threadIdx.x;
  if (t < 16) cnt[t] = 0;
  __syncthreads();
  int posA = 0, posB = 0, c0 = 0, b = 0;
  if (t < K) {
    b = (int)rois[t * 5];
    const float y1 = rois[t * 5 + 2] * SCALE_HW;
    const float y2 = rois[t * 5 + 4] * SCALE_HW;
#pragma unroll
    for (int oy = 0; oy < OH; ++oy)
      c0 += (iy_of(y1, y2, oy) < 80.0f) ? 1 : 0;   // monotonic in oy
    posA = atomicAdd(&cnt[b * 2 + 0], c0 * OW);
    posB = atomicAdd(&cnt[b * 2 + 1], (OH - c0) * OW);
  }
  __syncthreads();
  if (t == 0) {
    int acc = 0;
    for (int i = 0; i < 16; ++i) { soff[i] = acc; acc += cnt[i]; }
  }
  __syncthreads();
  if (t < 16) { ws[t] = cnt[t]; ws[16 + t] = soff[t]; }
  if (t < K) {
    ws[WS_KINFO_OFF + 3 * t + 0] = soff[b * 2 + 0] + posA;
    ws[WS_KINFO_OFF + 3 * t + 1] = soff[b * 2 + 1] + posB;
    ws[WS_KINFO_OFF + 3 * t + 2] = c0;
  }
}

__global__ __launch_bounds__(256) void precompute_kernel(
    const float* __restrict__ rois, const int* __restrict__ ws, int total,
    uint4* __restrict__ samples) {
  const int g = blockIdx.x * 256 + threadIdx.x;
  if (g >= total) return;
  const int k = g / OSP;
  const int s = g - k * OSP;
  const int oy = s / OW;
  const int ox = s - oy * OW;

  const float x1 = rois[k * 5 + 1] * SCALE_HW;
  const float y1 = rois[k * 5 + 2] * SCALE_HW;
  const float x2 = rois[k * 5 + 3] * SCALE_HW;
  const float y2 = rois[k * 5 + 4] * SCALE_HW;

  // ALIGNED=False index math collapses to ix = fx - 0.5
  const float ix = fmaf((float)ox * (1.0f / (OW - 1)), x2 - x1, x1) - 0.5f;
  const float iy = iy_of(y1, y2, oy);

  const float fx0 = floorf(ix);
  const float fy0 = floorf(iy);
  const int x0 = (int)fx0;
  const int y0 = (int)fy0;
  const float wx1 = ix - fx0;
  const float wy1 = iy - fy0;

  const bool vx0 = (x0 >= 0 && x0 < FM_W);
  const bool vx1 = (x0 + 1 >= 0 && x0 + 1 < FM_W);
  const unsigned vy0 = (y0 >= 0 && y0 < FM_H) ? 1u : 0u;
  const unsigned vy1 = (y0 + 1 >= 0 && y0 + 1 < FM_H) ? 1u : 0u;

  const int x0c = min(max(x0, 0), FM_W - 1);
  const int x1c = min(max(x0 + 1, 0), FM_W - 1);
  const int y0c = min(max(y0, 0), FM_H - 1);
  const int y1c = min(max(y0 + 1, 0), FM_H - 1);

  const int ca = ws[WS_KINFO_OFF + 3 * k + 0];
  const int cb = ws[WS_KINFO_OFF + 3 * k + 1];
  const int c0 = ws[WS_KINFO_OFF + 3 * k + 2];
  const int h = (oy >= c0) ? 1 : 0;   // == (iy >= 80) by monotonicity
  const int row0 = h ? 79 : 0;

  // Half-plane-local, stride-164 pixel coordinates.
  const int yl0 = y0c - row0;
  const int o00 = yl0 * LDSW + x0c;
  const int o01 = yl0 * LDSW + x1c;
  // Left-base: corners always {pix[bx], pix[bx+1]}; border cases carry zero
  // ax weight on the garbage side (pads zeroed in main kernel).
  const int bx = vx1 ? (o01 - 1) : o00;            // [-1, 13279]
  const unsigned bxs = (unsigned)(bx + FRONTPAD);  // 15 bits
  const unsigned dyr = (unsigned)(y1c - y0c);      // 0/1
  unsigned wq = (unsigned)(wy1 * 8192.0f + 0.5f);
  wq = wq > 8191u ? 8191u : wq;

  const __half2 axh = __floats2half2_rn((1.0f - wx1) * (vx0 ? 1.0f : 0.0f),
                                        wx1 * (vx1 ? 1.0f : 0.0f));
  uint4 sd;
  sd.x = bxs | (dyr << 15) | (wq << 16) | (vy0 << 29) | (vy1 << 30);
  sd.y = *(const unsigned*)&axh;
  sd.z = (unsigned)(k * (FM_C * OSP) + s);  // out index (+ c*OSP at store)
  sd.w = 0;

  const int pos = h ? (cb + (oy - c0) * OW + ox) : (ca + oy * OW + ox);
  samples[pos] = sd;
}

__global__ __launch_bounds__(MAIN_BLK) void roi_align_main_kernel(
    const float* __restrict__ feat, const int* __restrict__ ws,
    const uint4* __restrict__ samples, float* __restrict__ out) {
  // pixel = uint2 = 4 channels as 2x half2. [2 front pad][81x164][6 tail pad]
  __shared__ __align__(16) uint2 planeBuf[FRONTPAD + PL_PIX + TAILPAD];

  const int q = blockIdx.x;        // channel-quad index (0..63)
  const int b = blockIdx.y;
  const int h = blockIdx.z;
  const int t = threadIdx.x;
  const int row0 = h ? 79 : 0;
  const int c0ch = 4 * q;

  const int scount = ws[b * 2 + h];
  const int soff = ws[16 + b * 2 + h];
  const uint4* __restrict__ stream = samples + soff;

  // zero front pad, tail pad, and the 4 pad columns of each of 81 rows
  const uint2 zz = {0u, 0u};
  if (t < FRONTPAD) planeBuf[t] = zz;
  if (t < TAILPAD) planeBuf[FRONTPAD + PL_PIX + t] = zz;
  if (t < ROWS * 4) {
    const int y = t >> 2;
    planeBuf[FRONTPAD + y * LDSW + FM_W + (t & 3)] = zz;
  }

  // ---- NT-stage rows [row0, row0+81) of planes c0ch..c0ch+3 as half2x2
  {
    const f4* __restrict__ s0 =
        (const f4*)(feat + ((size_t)b * FM_C + c0ch) * PLANE) + row0 * ROW_F4;
    const f4* __restrict__ s1 = s0 + PLANE4;
    const f4* __restrict__ s2 = s0 + 2 * PLANE4;
    const f4* __restrict__ s3 = s0 + 3 * PLANE4;
    for (int i = t; i < PL_F4; i += MAIN_BLK) {
      const f4 a = __builtin_nontemporal_load(&s0[i]);
      const f4 bb = __builtin_nontemporal_load(&s1[i]);
      const f4 c = __builtin_nontemporal_load(&s2[i]);
      const f4 d = __builtin_nontemporal_load(&s3[i]);
      const int y = (int)((unsigned)i / ROW_F4);
      const int j = i - y * ROW_F4;
      // pixel p: {half2(a,b), half2(c,d)}
      const __half2 p0l = __floats2half2_rn(a.x, bb.x);
      const __half2 p0h = __floats2half2_rn(c.x, d.x);
      const __half2 p1l = __floats2half2_rn(a.y, bb.y);
      const __half2 p1h = __floats2half2_rn(c.y, d.y);
      const __half2 p2l = __floats2half2_rn(a.z, bb.z);
      const __half2 p2h = __floats2half2_rn(c.z, d.z);
      const __half2 p3l = __floats2half2_rn(a.w, bb.w);
      const __half2 p3h = __floats2half2_rn(c.w, d.w);
      uint4 u01, u23;
      u01.x = *(const unsigned*)&p0l;
      u01.y = *(const unsigned*)&p0h;
      u01.z = *(const unsigned*)&p1l;
      u01.w = *(const unsigned*)&p1h;
      u23.x = *(const unsigned*)&p2l;
      u23.y = *(const unsigned*)&p2h;
      u23.z = *(const unsigned*)&p3l;
      u23.w = *(const unsigned*)&p3h;
      uint4* __restrict__ dst =
          (uint4*)&planeBuf[FRONTPAD + y * LDSW + 4 * j];  // 16B-aligned
      dst[0] = u01;
      dst[1] = u23;
    }
  }
  __syncthreads();

  // ---- gather: one descriptor serves channels c0ch..c0ch+3
  const uint2* __restrict__ pb = planeBuf;
  float* __restrict__ outc = out + (size_t)c0ch * OSP;
#pragma unroll 2
  for (int w = t; w < scount; w += MAIN_BLK) {
    const uint4 sd = stream[w];
    const int bxs = (int)(sd.x & 0x7FFFu);
    const int o10 = bxs + (int)((sd.x >> 15) & 1u) * LDSW;

    // adjacent pixel pairs -> merged ds_read2_b64 per row
    const uint2 L0 = pb[bxs];
    const uint2 R0 = pb[bxs + 1];
    const uint2 L1 = pb[o10];
    const uint2 R1 = pb[o10 + 1];

    const __half2 ax = *(const __half2*)&sd.y;
    const __half2 axl = __half2half2(__low2half(ax));
    const __half2 axr = __half2half2(__high2half(ax));

    const __half2 hx0l = __hfma2(*(const __half2*)&R0.x, axr,
                                 __hmul2(*(const __half2*)&L0.x, axl));
    const __half2 hx0h = __hfma2(*(const __half2*)&R0.y, axr,
                                 __hmul2(*(const __half2*)&L0.y, axl));
    const __half2 hx1l = __hfma2(*(const __half2*)&R1.x, axr,
                                 __hmul2(*(const __half2*)&L1.x, axl));
    const __half2 hx1h = __hfma2(*(const __half2*)&R1.y, axr,
                                 __hmul2(*(const __half2*)&L1.y, axl));

    const float wy1 = (float)((sd.x >> 16) & 0x1FFFu) * (1.0f / 8192.0f);
    const float ay0 = ((sd.x >> 29) & 1u) ? (1.0f - wy1) : 0.0f;
    const float ay1 = ((sd.x >> 30) & 1u) ? wy1 : 0.0f;

    const float vA = ay0 * __low2float(hx0l) + ay1 * __low2float(hx1l);
    const float vB = ay0 * __high2float(hx0l) + ay1 * __high2float(hx1l);
    const float vC = ay0 * __low2float(hx0h) + ay1 * __low2float(hx1h);
    const float vD = ay0 * __high2float(hx0h) + ay1 * __high2float(hx1h);

    float* __restrict__ dst = outc + sd.z;
    dst[0] = vA;
    dst[OSP] = vB;
    dst[2 * OSP] = vC;
    dst[3 * OSP] = vD;
  }
}

extern "C" void kernel_launch(void* const* d_in, const int* in_sizes, int n_in,
                              void* d_out, int out_size, void* d_ws, size_t ws_size,
                              hipStream_t stream) {
  const float* feat = (const float*)d_in[0];
  const float* rois = (const float*)d_in[1];
  float* out = (float*)d_out;
  int* ws = (int*)d_ws;
  uint4* samples = (uint4*)((char*)d_ws + WS_SAMPLES_BYTE_OFF);

  const int K = in_sizes[1] / 5;  // 1024
  const int total = K * OSP;

  setup_kernel<<<1, 1024, 0, stream>>>(rois, K, ws);
  precompute_kernel<<<(total + 255) / 256, 256, 0, stream>>>(rois, ws, total,
                                                             samples);
  roi_align_main_kernel<<<dim3(FM_C / 4, FM_N, 2), MAIN_BLK, 0, stream>>>(
      feat, ws, samples, out);
}